// Round 1
// baseline (2480.762 us; speedup 1.0000x reference)
//
#include <hip/hip_runtime.h>
#include <math.h>

#define NE 160000
#define NN 10000
#define SCR 41   // per-lane LDS scratch stride (odd -> conflict-free)

#define DEV __device__ __forceinline__

DEV float fsilu(float x) { return x / (1.0f + __expf(-x)); }
DEV float fsig(float x)  { return 1.0f / (1.0f + __expf(-x)); }

// acc[64] += x_row(per-lane, global, KC floats, 16B aligned) @ W(uniform, KCx64 row-major)
template<int KC>
DEV void gemm_g(const float* src, const float* __restrict__ w, float acc[64]) {
#pragma unroll 1
  for (int kk = 0; kk < KC; kk += 4) {
    const float4 x4 = *(const float4*)(src + kk);
    const float* wr = w + (size_t)kk * 64;
#pragma unroll
    for (int j = 0; j < 64; ++j) acc[j] = fmaf(x4.x, wr[j], acc[j]);
#pragma unroll
    for (int j = 0; j < 64; ++j) acc[j] = fmaf(x4.y, wr[64 + j], acc[j]);
#pragma unroll
    for (int j = 0; j < 64; ++j) acc[j] = fmaf(x4.z, wr[128 + j], acc[j]);
#pragma unroll
    for (int j = 0; j < 64; ++j) acc[j] = fmaf(x4.w, wr[192 + j], acc[j]);
  }
}

// acc[64] += lrow[0..K) (per-lane LDS) @ W(uniform, Kx64)
template<int K>
DEV void gemm_l(const float* lrow, const float* __restrict__ w, float acc[64]) {
#pragma unroll 1
  for (int k = 0; k < K; ++k) {
    const float x = lrow[k];
    const float* wr = w + (size_t)k * 64;
#pragma unroll
    for (int j = 0; j < 64; ++j) acc[j] = fmaf(x, wr[j], acc[j]);
  }
}

DEV void store64(float* dst, const float* a) {
#pragma unroll
  for (int j = 0; j < 64; j += 4)
    *(float4*)(dst + j) = make_float4(a[j], a[j+1], a[j+2], a[j+3]);
}

// ---------------- chem MLP (272->64->64) + u scalar head ----------------
__global__ void __launch_bounds__(64)
k_chem(const float* __restrict__ h, const float* __restrict__ na,
       const float* __restrict__ ea, const int* __restrict__ edges,
       const float* __restrict__ w1, const float* __restrict__ b1,
       const float* __restrict__ w2, const float* __restrict__ b2,
       const float* __restrict__ wu1, const float* __restrict__ bu1,
       const float* __restrict__ wu2, const float* __restrict__ bu2,
       float* __restrict__ chem, float* __restrict__ ue) {
  __shared__ float scr[64 * SCR];
  int e = blockIdx.x * 64 + threadIdx.x;
  if (e >= NE) return;
  float* lrow = scr + threadIdx.x * SCR;
  int r = edges[e], c = edges[NE + e];

  float acc[64];
#pragma unroll
  for (int j = 0; j < 64; ++j) acc[j] = b1[j];
  gemm_g<64>(h  + (size_t)r * 64, w1,            acc);
  gemm_g<64>(h  + (size_t)c * 64, w1 +  64 * 64, acc);
  gemm_g<64>(na + (size_t)r * 64, w1 + 128 * 64, acc);
  gemm_g<64>(na + (size_t)c * 64, w1 + 192 * 64, acc);
  gemm_g<16>(ea + (size_t)e * 16, w1 + 256 * 64, acc);

  float a2[64];
#pragma unroll
  for (int j = 0; j < 64; ++j) a2[j] = b2[j];
#pragma unroll
  for (int j = 0; j < 32; ++j) lrow[j] = fsilu(acc[j]);
  gemm_l<32>(lrow, w2, a2);
#pragma unroll
  for (int j = 0; j < 32; ++j) lrow[j] = fsilu(acc[32 + j]);
  gemm_l<32>(lrow, w2 + 32 * 64, a2);
#pragma unroll
  for (int j = 0; j < 64; ++j) a2[j] = fsilu(a2[j]);   // chem
  store64(chem + (size_t)e * 64, a2);

  // u = silu(chem@wu1+bu1)@wu2 + bu2
  float a3[64];
#pragma unroll
  for (int j = 0; j < 64; ++j) a3[j] = bu1[j];
#pragma unroll
  for (int j = 0; j < 32; ++j) lrow[j] = a2[j];
  gemm_l<32>(lrow, wu1, a3);
#pragma unroll
  for (int j = 0; j < 32; ++j) lrow[j] = a2[32 + j];
  gemm_l<32>(lrow, wu1 + 32 * 64, a3);
  float u = bu2[0];
#pragma unroll
  for (int k = 0; k < 64; ++k) u = fmaf(fsilu(a3[k]), wu2[k], u);
  ue[e] = u;
}

// ------------- pos MLP (36->64->64) + x scalar head + x_trans atomics -------------
__global__ void __launch_bounds__(64)
k_pos(const float* __restrict__ coord, const float* __restrict__ nv,
      const float* __restrict__ ea, const int* __restrict__ edges,
      const float* __restrict__ w1, const float* __restrict__ b1,
      const float* __restrict__ w2, const float* __restrict__ b2,
      const float* __restrict__ wx1, const float* __restrict__ bx1,
      const float* __restrict__ wx2, const float* __restrict__ bx2,
      const float* __restrict__ ue,
      float* __restrict__ pos, float* __restrict__ x_sum, float* __restrict__ cntf) {
  __shared__ float scr[64 * SCR];
  int e = blockIdx.x * 64 + threadIdx.x;
  if (e >= NE) return;
  float* lrow = scr + threadIdx.x * SCR;
  int r = edges[e], c = edges[NE + e];

  float dx = coord[r * 3 + 0] - coord[c * 3 + 0];
  float dy = coord[r * 3 + 1] - coord[c * 3 + 1];
  float dz = coord[r * 3 + 2] - coord[c * 3 + 2];
  float nrm = sqrtf(dx * dx + dy * dy + dz * dz);
  float inv = 1.0f / (nrm + 1e-8f);
  dx *= inv; dy *= inv; dz *= inv;
  float ir = dx * dx + dy * dy + dz * dz;

#pragma unroll
  for (int v = 0; v < 5; ++v) {
    float s = 0.f;
#pragma unroll
    for (int d = 0; d < 3; ++d)
      s += nv[(size_t)r * 15 + v * 3 + d] * nv[(size_t)c * 15 + v * 3 + d];
    lrow[v] = s;
  }
  float cexp = -0.5f;
#pragma unroll
  for (int k = 0; k < 15; ++k) { lrow[5 + k] = __expf(ir * cexp); cexp *= (1.0f / 2.25f); }
#pragma unroll
  for (int k = 0; k < 16; ++k) lrow[20 + k] = ea[(size_t)e * 16 + k];

  float acc[64];
#pragma unroll
  for (int j = 0; j < 64; ++j) acc[j] = b1[j];
  gemm_l<36>(lrow, w1, acc);

  float a2[64];
#pragma unroll
  for (int j = 0; j < 64; ++j) a2[j] = b2[j];
#pragma unroll
  for (int j = 0; j < 32; ++j) lrow[j] = fsilu(acc[j]);
  gemm_l<32>(lrow, w2, a2);
#pragma unroll
  for (int j = 0; j < 32; ++j) lrow[j] = fsilu(acc[32 + j]);
  gemm_l<32>(lrow, w2 + 32 * 64, a2);
#pragma unroll
  for (int j = 0; j < 64; ++j) a2[j] = fsilu(a2[j]);  // pos
  store64(pos + (size_t)e * 64, a2);

  // x scalar = silu(pos@wx1+bx1)@wx2 + bx2
  float a3[64];
#pragma unroll
  for (int j = 0; j < 64; ++j) a3[j] = bx1[j];
#pragma unroll
  for (int j = 0; j < 32; ++j) lrow[j] = a2[j];
  gemm_l<32>(lrow, wx1, a3);
#pragma unroll
  for (int j = 0; j < 32; ++j) lrow[j] = a2[32 + j];
  gemm_l<32>(lrow, wx1 + 32 * 64, a3);
  float xs = bx2[0];
#pragma unroll
  for (int k = 0; k < 64; ++k) xs = fmaf(fsilu(a3[k]), wx2[k], xs);

  float t = ue[e] * xs;
  atomicAdd(&x_sum[r * 3 + 0], dx * t);
  atomicAdd(&x_sum[r * 3 + 1], dy * t);
  atomicAdd(&x_sum[r * 3 + 2], dz * t);
  atomicAdd(&cntf[r], 1.0f);
}

// ---------------- z = silu(chem@Wsh+b)*pos; z *= sigmoid(z@watt+batt) ----------------
__global__ void __launch_bounds__(64)
k_z(const float* __restrict__ chem, const float* __restrict__ pos,
    const float* __restrict__ wsh, const float* __restrict__ bsh,
    const float* __restrict__ watt, const float* __restrict__ batt,
    float* __restrict__ z) {
  int e = blockIdx.x * 64 + threadIdx.x;
  if (e >= NE) return;
  float acc[64];
#pragma unroll
  for (int j = 0; j < 64; ++j) acc[j] = bsh[j];
  gemm_g<64>(chem + (size_t)e * 64, wsh, acc);
  float z0[64];
#pragma unroll
  for (int j = 0; j < 64; j += 4) {
    float4 p4 = *(const float4*)(pos + (size_t)e * 64 + j);
    z0[j + 0] = fsilu(acc[j + 0]) * p4.x;
    z0[j + 1] = fsilu(acc[j + 1]) * p4.y;
    z0[j + 2] = fsilu(acc[j + 2]) * p4.z;
    z0[j + 3] = fsilu(acc[j + 3]) * p4.w;
  }
  float a = batt[0];
#pragma unroll
  for (int k = 0; k < 64; ++k) a = fmaf(z0[k], watt[k], a);
  float sg = fsig(a);
#pragma unroll
  for (int j = 0; j < 64; ++j) z0[j] *= sg;
  store64(z + (size_t)e * 64, z0);
}

// ---------------- per-head k_, v, b ----------------
__global__ void __launch_bounds__(64)
k_kvb(const float* __restrict__ z, const float* __restrict__ wk,
      const float* __restrict__ wv, const float* __restrict__ wb,
      float* __restrict__ kb, float* __restrict__ vb, float* __restrict__ bb) {
  int e = blockIdx.x * 64 + threadIdx.x;
  if (e >= NE) return;
  const float* zr = z + (size_t)e * 64;
  float acc[64];
#pragma unroll
  for (int j = 0; j < 64; ++j) acc[j] = 0.f;
  gemm_g<64>(zr, wk, acc);
  store64(kb + (size_t)e * 64, acc);
#pragma unroll
  for (int j = 0; j < 64; ++j) acc[j] = 0.f;
  gemm_g<64>(zr, wv, acc);
  store64(vb + (size_t)e * 64, acc);
  float b = 0.f;
#pragma unroll 1
  for (int kk = 0; kk < 64; kk += 4) {
    float4 z4 = *(const float4*)(zr + kk);
    b = fmaf(z4.x, wb[kk + 0], b); b = fmaf(z4.y, wb[kk + 1], b);
    b = fmaf(z4.z, wb[kk + 2], b); b = fmaf(z4.w, wb[kk + 3], b);
  }
  bb[e] = b;
}

// ---------------- per-head attention + accumulate into m ----------------
__global__ void __launch_bounds__(64)
k_attn(const float* __restrict__ z, const float* __restrict__ kb,
       const float* __restrict__ vb, const float* __restrict__ bb,
       const int* __restrict__ klist,
       const float* __restrict__ wq, const float* __restrict__ wg,
       const float* __restrict__ bg,
       const float* __restrict__ wout, const float* __restrict__ bout,
       float* __restrict__ m, int first) {
  __shared__ float scr[64 * SCR];
  int e = blockIdx.x * 64 + threadIdx.x;
  if (e >= NE) return;
  float* lrow = scr + threadIdx.x * SCR;
  const float* zr = z + (size_t)e * 64;

  float q[64];
#pragma unroll
  for (int j = 0; j < 64; ++j) q[j] = 0.f;
  gemm_g<64>(zr, wq, q);

  int i2[8], j2[8];
#pragma unroll
  for (int kn = 0; kn < 8; ++kn) {
    i2[kn] = klist[(size_t)e * 16 + kn];
    j2[kn] = klist[(size_t)e * 16 + 8 + kn];
  }
  float alpha[8];
#pragma unroll
  for (int kn = 0; kn < 8; ++kn) {
    if (i2[kn] < 0) { alpha[kn] = -10000.0f; }
    else {
      const float* kr = kb + (size_t)i2[kn] * 64;
      float d0 = 0.f, d1 = 0.f, d2 = 0.f, d3 = 0.f;
#pragma unroll
      for (int kk = 0; kk < 64; kk += 4) {
        float4 k4 = *(const float4*)(kr + kk);
        d0 = fmaf(k4.x, q[kk + 0], d0); d1 = fmaf(k4.y, q[kk + 1], d1);
        d2 = fmaf(k4.z, q[kk + 2], d2); d3 = fmaf(k4.w, q[kk + 3], d3);
      }
      alpha[kn] = (d0 + d1 + d2 + d3) * 0.125f + bb[j2[kn]];
    }
  }
  float mx = alpha[0];
#pragma unroll
  for (int kn = 1; kn < 8; ++kn) mx = fmaxf(mx, alpha[kn]);
  float p[8], s = 0.f;
#pragma unroll
  for (int kn = 0; kn < 8; ++kn) { p[kn] = __expf(alpha[kn] - mx); s += p[kn]; }
  float is = 1.0f / s;

  float out[64];
#pragma unroll
  for (int j = 0; j < 64; ++j) out[j] = 0.f;
#pragma unroll
  for (int kn = 0; kn < 8; ++kn) {
    int vi = (i2[kn] < 0) ? (NE - 1) : i2[kn];   // jax v[-1] wraps
    const float* vr = vb + (size_t)vi * 64;
    float pk = p[kn] * is;
#pragma unroll
    for (int kk = 0; kk < 64; kk += 4) {
      float4 v4 = *(const float4*)(vr + kk);
      out[kk + 0] = fmaf(pk, v4.x, out[kk + 0]);
      out[kk + 1] = fmaf(pk, v4.y, out[kk + 1]);
      out[kk + 2] = fmaf(pk, v4.z, out[kk + 2]);
      out[kk + 3] = fmaf(pk, v4.w, out[kk + 3]);
    }
  }
  // g gate
  float g[64];
#pragma unroll
  for (int j = 0; j < 64; ++j) g[j] = bg[j];
  gemm_g<64>(zr, wg, g);
#pragma unroll
  for (int j = 0; j < 64; ++j) out[j] *= fsig(g[j]);   // ho

  // m += ho @ wout_head (+ b_out on first head)
  float mm[64];
  if (first) {
#pragma unroll
    for (int j = 0; j < 64; ++j) mm[j] = bout[j];
  } else {
#pragma unroll
    for (int j = 0; j < 64; j += 4) {
      float4 m4 = *(const float4*)(m + (size_t)e * 64 + j);
      mm[j] = m4.x; mm[j + 1] = m4.y; mm[j + 2] = m4.z; mm[j + 3] = m4.w;
    }
  }
#pragma unroll
  for (int j = 0; j < 32; ++j) lrow[j] = out[j];
  gemm_l<32>(lrow, wout, mm);
#pragma unroll
  for (int j = 0; j < 32; ++j) lrow[j] = out[32 + j];
  gemm_l<32>(lrow, wout + 32 * 64, mm);
  store64(m + (size_t)e * 64, mm);
}

// ---------------- scatter m into m_sum ----------------
__global__ void __launch_bounds__(256)
k_scatter(const float* __restrict__ m, const int* __restrict__ edges,
          float* __restrict__ m_sum) {
  int i = blockIdx.x * 256 + threadIdx.x;
  if (i >= NE * 64) return;
  int e = i >> 6, j = i & 63;
  atomicAdd(&m_sum[(size_t)edges[e] * 64 + j], m[i]);
}

// ---------------- final node update ----------------
__global__ void __launch_bounds__(64)
k_final(const float* __restrict__ h, const float* __restrict__ na,
        const float* __restrict__ coord, const float* __restrict__ icoord,
        const float* __restrict__ m_sum, const float* __restrict__ x_sum,
        const float* __restrict__ cntf,
        const float* __restrict__ wh1, const float* __restrict__ bh1,
        const float* __restrict__ wh2, const float* __restrict__ bh2,
        float* __restrict__ out) {
  __shared__ float scr[64 * SCR];
  int n = blockIdx.x * 64 + threadIdx.x;
  if (n >= NN) return;
  float* lrow = scr + threadIdx.x * SCR;
  float invc = 1.0f / fmaxf(cntf[n], 1.0f);

#pragma unroll
  for (int d = 0; d < 3; ++d)
    out[(size_t)NN * 64 + n * 3 + d] =
        0.2f * icoord[n * 3 + d] + 0.8f * coord[n * 3 + d] + x_sum[n * 3 + d] * invc;

  float acc[64];
#pragma unroll
  for (int j = 0; j < 64; ++j) acc[j] = bh1[j];
  gemm_g<64>(h  + (size_t)n * 64, wh1,           acc);
  gemm_g<64>(na + (size_t)n * 64, wh1 + 64 * 64, acc);
  float macc[64];
#pragma unroll
  for (int j = 0; j < 64; ++j) macc[j] = 0.f;
  gemm_g<64>(m_sum + (size_t)n * 64, wh1 + 128 * 64, macc);
#pragma unroll
  for (int j = 0; j < 64; ++j) acc[j] = fmaf(invc, macc[j], acc[j]);

  float a2[64];
#pragma unroll
  for (int j = 0; j < 64; ++j) a2[j] = bh2[j];
#pragma unroll
  for (int j = 0; j < 32; ++j) lrow[j] = fsilu(acc[j]);
  gemm_l<32>(lrow, wh2, a2);
#pragma unroll
  for (int j = 0; j < 32; ++j) lrow[j] = fsilu(acc[32 + j]);
  gemm_l<32>(lrow, wh2 + 32 * 64, a2);

#pragma unroll
  for (int j = 0; j < 64; ++j) a2[j] += h[(size_t)n * 64 + j];
  store64(out + (size_t)n * 64, a2);
}

extern "C" void kernel_launch(void* const* d_in, const int* in_sizes, int n_in,
                              void* d_out, int out_size, void* d_ws, size_t ws_size,
                              hipStream_t stream) {
  (void)in_sizes; (void)n_in; (void)out_size; (void)ws_size;
  const float* h      = (const float*)d_in[0];
  const float* coord  = (const float*)d_in[1];
  const int*   edges  = (const int*)  d_in[2];
  const float* nvecs  = (const float*)d_in[3];
  const float* ea     = (const float*)d_in[4];
  const float* na     = (const float*)d_in[5];
  const float* icoord = (const float*)d_in[6];
  const int*   klist  = (const int*)  d_in[7];
  const float* w_chem1 = (const float*)d_in[8];
  const float* b_chem1 = (const float*)d_in[9];
  const float* w_chem2 = (const float*)d_in[10];
  const float* b_chem2 = (const float*)d_in[11];
  const float* w_pos1  = (const float*)d_in[12];
  const float* b_pos1  = (const float*)d_in[13];
  const float* w_pos2  = (const float*)d_in[14];
  const float* b_pos2  = (const float*)d_in[15];
  const float* w_sh    = (const float*)d_in[16];
  const float* b_sh    = (const float*)d_in[17];
  const float* w_att   = (const float*)d_in[18];
  const float* b_att   = (const float*)d_in[19];
  const float* wq      = (const float*)d_in[20];
  const float* wk      = (const float*)d_in[21];
  const float* wv      = (const float*)d_in[22];
  const float* wb      = (const float*)d_in[23];
  const float* wg      = (const float*)d_in[24];
  const float* bg      = (const float*)d_in[25];
  const float* w_out   = (const float*)d_in[26];
  const float* b_out   = (const float*)d_in[27];
  const float* wu1     = (const float*)d_in[28];
  const float* bu1     = (const float*)d_in[29];
  const float* wu2     = (const float*)d_in[30];
  const float* bu2     = (const float*)d_in[31];
  const float* wx1     = (const float*)d_in[32];
  const float* bx1     = (const float*)d_in[33];
  const float* wx2     = (const float*)d_in[34];
  const float* bx2     = (const float*)d_in[35];
  const float* wh1     = (const float*)d_in[36];
  const float* bh1     = (const float*)d_in[37];
  const float* wh2     = (const float*)d_in[38];
  const float* bh2     = (const float*)d_in[39];

  float* out = (float*)d_out;
  float* ws  = (float*)d_ws;
  // workspace layout (~168 MB)
  float* z     = ws;
  float* bufA  = z    + (size_t)NE * 64;   // chem, later k_
  float* bufB  = bufA + (size_t)NE * 64;   // pos,  later v
  float* mbuf  = bufB + (size_t)NE * 64;   // m accumulator (E x 64)
  float* ue    = mbuf + (size_t)NE * 64;   // E
  float* be    = ue   + NE;                // E
  float* m_sum = be   + NE;                // N x 64
  float* x_sum = m_sum + (size_t)NN * 64;  // N x 3
  float* cntf  = x_sum + (size_t)NN * 3;   // N

  hipMemsetAsync(m_sum, 0, (size_t)(NN * 64 + NN * 3 + NN) * sizeof(float), stream);

  dim3 blk(64), grid((NE + 63) / 64);
  k_chem<<<grid, blk, 0, stream>>>(h, na, ea, edges, w_chem1, b_chem1, w_chem2, b_chem2,
                                   wu1, bu1, wu2, bu2, bufA, ue);
  k_pos<<<grid, blk, 0, stream>>>(coord, nvecs, ea, edges, w_pos1, b_pos1, w_pos2, b_pos2,
                                  wx1, bx1, wx2, bx2, ue, bufB, x_sum, cntf);
  k_z<<<grid, blk, 0, stream>>>(bufA, bufB, w_sh, b_sh, w_att, b_att, z);
  for (int hd = 0; hd < 4; ++hd) {
    k_kvb<<<grid, blk, 0, stream>>>(z, wk + hd * 4096, wv + hd * 4096, wb + hd * 64,
                                    bufA, bufB, be);
    k_attn<<<grid, blk, 0, stream>>>(z, bufA, bufB, be, klist,
                                     wq + hd * 4096, wg + hd * 4096, bg + hd * 64,
                                     w_out + hd * 64 * 64, b_out, mbuf, hd == 0 ? 1 : 0);
  }
  k_scatter<<<dim3((NE * 64) / 256), dim3(256), 0, stream>>>(mbuf, edges, m_sum);
  k_final<<<dim3((NN + 63) / 64), blk, 0, stream>>>(h, na, coord, icoord, m_sum, x_sum,
                                                    cntf, wh1, bh1, wh2, bh2, out);
}

// Round 2
// 2206.332 us; speedup vs baseline: 1.1244x; 1.1244x over previous
//
#include <hip/hip_runtime.h>
#include <math.h>

#define NE 160000
#define NN 10000

#define DEV __device__ __forceinline__

DEV float fsilu(float x) { return x / (1.0f + __expf(-x)); }
DEV float fsig(float x)  { return 1.0f / (1.0f + __expf(-x)); }

// acc[32] += x[k] * w[k*64 + j], k in [0,K), j in [0,32). w pre-offset to chunk.
template<int K>
DEV void gemm32(const float* src, const float* __restrict__ w, float (&acc)[32]) {
#pragma unroll 1
  for (int k = 0; k < K; k += 2) {
    const float2 x2 = *(const float2*)(src + k);
    const float* wr = w + (size_t)k * 64;
#pragma unroll
    for (int j = 0; j < 32; ++j) acc[j] = fmaf(x2.x, wr[j], acc[j]);
#pragma unroll
    for (int j = 0; j < 32; ++j) acc[j] = fmaf(x2.y, wr[64 + j], acc[j]);
  }
}

DEV void store32(float* dst, const float (&a)[32]) {
#pragma unroll
  for (int j = 0; j < 32; j += 4)
    *(float4*)(dst + j) = make_float4(a[j], a[j+1], a[j+2], a[j+3]);
}

// ---------------- chem MLP (272->64->64) + u scalar head ----------------
__global__ void __launch_bounds__(256)
k_chem(const float* __restrict__ h, const float* __restrict__ na,
       const float* __restrict__ ea, const int* __restrict__ edges,
       const float* __restrict__ w1, const float* __restrict__ b1,
       const float* __restrict__ w2, const float* __restrict__ b2,
       const float* __restrict__ wu1, const float* __restrict__ bu1,
       const float* __restrict__ wu2, const float* __restrict__ bu2,
       float* __restrict__ scr,   // E x 64 staging (kb region)
       float* __restrict__ chem,  // E x 64 (mbuf region)
       float* __restrict__ ue) {
  int e = blockIdx.x * 256 + threadIdx.x;
  if (e >= NE) return;
  int r = edges[e], c = edges[NE + e];
  const float* hr = h  + (size_t)r * 64;
  const float* hc = h  + (size_t)c * 64;
  const float* nr = na + (size_t)r * 64;
  const float* nc = na + (size_t)c * 64;
  const float* er = ea + (size_t)e * 16;
  float* srow = scr  + (size_t)e * 64;
  float* crow = chem + (size_t)e * 64;

  // layer 1: 272 -> 64, silu, staged to srow
#pragma unroll 1
  for (int cc = 0; cc < 64; cc += 32) {
    float acc[32];
#pragma unroll
    for (int j = 0; j < 32; ++j) acc[j] = b1[cc + j];
    gemm32<64>(hr, w1 + cc, acc);
    gemm32<64>(hc, w1 +  64 * 64 + cc, acc);
    gemm32<64>(nr, w1 + 128 * 64 + cc, acc);
    gemm32<64>(nc, w1 + 192 * 64 + cc, acc);
    gemm32<16>(er, w1 + 256 * 64 + cc, acc);
#pragma unroll
    for (int j = 0; j < 32; ++j) acc[j] = fsilu(acc[j]);
    store32(srow + cc, acc);
  }
  // layer 2: 64 -> 64, silu -> chem
#pragma unroll 1
  for (int cc = 0; cc < 64; cc += 32) {
    float acc[32];
#pragma unroll
    for (int j = 0; j < 32; ++j) acc[j] = b2[cc + j];
    gemm32<64>(srow, w2 + cc, acc);
#pragma unroll
    for (int j = 0; j < 32; ++j) acc[j] = fsilu(acc[j]);
    store32(crow + cc, acc);
  }
  // u head: silu(chem@wu1+bu1)@wu2 + bu2
  float u = bu2[0];
#pragma unroll 1
  for (int cc = 0; cc < 64; cc += 32) {
    float acc[32];
#pragma unroll
    for (int j = 0; j < 32; ++j) acc[j] = bu1[cc + j];
    gemm32<64>(crow, wu1 + cc, acc);
#pragma unroll
    for (int j = 0; j < 32; ++j) u = fmaf(fsilu(acc[j]), wu2[cc + j], u);
  }
  ue[e] = u;
}

// ------------- pos MLP (36->64->64) + x scalar head + x_trans atomics -------------
__global__ void __launch_bounds__(256)
k_pos(const float* __restrict__ coord, const float* __restrict__ nv,
      const float* __restrict__ ea, const int* __restrict__ edges,
      const float* __restrict__ w1, const float* __restrict__ b1,
      const float* __restrict__ w2, const float* __restrict__ b2,
      const float* __restrict__ wx1, const float* __restrict__ bx1,
      const float* __restrict__ wx2, const float* __restrict__ bx2,
      const float* __restrict__ ue,
      float* __restrict__ scrA,  // E x 64 staging (kb region): 36 inputs
      float* __restrict__ scrB,  // E x 64 staging (z region): layer1 acts
      float* __restrict__ pos,   // E x 64 (vb region)
      float* __restrict__ x_sum, float* __restrict__ cntf) {
  int e = blockIdx.x * 256 + threadIdx.x;
  if (e >= NE) return;
  int r = edges[e], c = edges[NE + e];
  float* arow = scrA + (size_t)e * 64;
  float* brow = scrB + (size_t)e * 64;
  float* prow = pos  + (size_t)e * 64;

  float dx = coord[r * 3 + 0] - coord[c * 3 + 0];
  float dy = coord[r * 3 + 1] - coord[c * 3 + 1];
  float dz = coord[r * 3 + 2] - coord[c * 3 + 2];
  float nrm = sqrtf(dx * dx + dy * dy + dz * dz);
  float inv = 1.0f / (nrm + 1e-8f);
  dx *= inv; dy *= inv; dz *= inv;
  float ir = dx * dx + dy * dy + dz * dz;

  {
    float in[36];
#pragma unroll
    for (int v = 0; v < 5; ++v) {
      float s = 0.f;
#pragma unroll
      for (int d = 0; d < 3; ++d)
        s += nv[(size_t)r * 15 + v * 3 + d] * nv[(size_t)c * 15 + v * 3 + d];
      in[v] = s;
    }
    float cexp = -0.5f;
#pragma unroll
    for (int k = 0; k < 15; ++k) { in[5 + k] = __expf(ir * cexp); cexp *= (1.0f / 2.25f); }
#pragma unroll
    for (int k = 0; k < 16; ++k) in[20 + k] = ea[(size_t)e * 16 + k];
#pragma unroll
    for (int k = 0; k < 36; k += 4)
      *(float4*)(arow + k) = make_float4(in[k], in[k+1], in[k+2], in[k+3]);
  }

  // layer 1: 36 -> 64 silu -> brow
#pragma unroll 1
  for (int cc = 0; cc < 64; cc += 32) {
    float acc[32];
#pragma unroll
    for (int j = 0; j < 32; ++j) acc[j] = b1[cc + j];
    gemm32<36>(arow, w1 + cc, acc);
#pragma unroll
    for (int j = 0; j < 32; ++j) acc[j] = fsilu(acc[j]);
    store32(brow + cc, acc);
  }
  // layer 2: 64 -> 64 silu -> pos
#pragma unroll 1
  for (int cc = 0; cc < 64; cc += 32) {
    float acc[32];
#pragma unroll
    for (int j = 0; j < 32; ++j) acc[j] = b2[cc + j];
    gemm32<64>(brow, w2 + cc, acc);
#pragma unroll
    for (int j = 0; j < 32; ++j) acc[j] = fsilu(acc[j]);
    store32(prow + cc, acc);
  }
  // x head
  float xs = bx2[0];
#pragma unroll 1
  for (int cc = 0; cc < 64; cc += 32) {
    float acc[32];
#pragma unroll
    for (int j = 0; j < 32; ++j) acc[j] = bx1[cc + j];
    gemm32<64>(prow, wx1 + cc, acc);
#pragma unroll
    for (int j = 0; j < 32; ++j) xs = fmaf(fsilu(acc[j]), wx2[cc + j], xs);
  }

  float t = ue[e] * xs;
  atomicAdd(&x_sum[r * 3 + 0], dx * t);
  atomicAdd(&x_sum[r * 3 + 1], dy * t);
  atomicAdd(&x_sum[r * 3 + 2], dz * t);
  atomicAdd(&cntf[r], 1.0f);
}

// ---------------- z = silu(chem@Wsh+b)*pos; z *= sigmoid(z@watt+batt) ----------------
__global__ void __launch_bounds__(256)
k_z(const float* __restrict__ chem, const float* __restrict__ pos,
    const float* __restrict__ wsh, const float* __restrict__ bsh,
    const float* __restrict__ watt, const float* __restrict__ batt,
    float* __restrict__ z) {
  int e = blockIdx.x * 256 + threadIdx.x;
  if (e >= NE) return;
  const float* crow = chem + (size_t)e * 64;
  const float* prow = pos  + (size_t)e * 64;
  float z0[64];
#pragma unroll 1
  for (int cc = 0; cc < 64; cc += 32) {
    float acc[32];
#pragma unroll
    for (int j = 0; j < 32; ++j) acc[j] = bsh[cc + j];
    gemm32<64>(crow, wsh + cc, acc);
#pragma unroll
    for (int j = 0; j < 32; j += 4) {
      float4 p4 = *(const float4*)(prow + cc + j);
      z0[cc + j + 0] = fsilu(acc[j + 0]) * p4.x;
      z0[cc + j + 1] = fsilu(acc[j + 1]) * p4.y;
      z0[cc + j + 2] = fsilu(acc[j + 2]) * p4.z;
      z0[cc + j + 3] = fsilu(acc[j + 3]) * p4.w;
    }
  }
  float a = batt[0];
#pragma unroll
  for (int k = 0; k < 64; ++k) a = fmaf(z0[k], watt[k], a);
  float sg = fsig(a);
  float* zr = z + (size_t)e * 64;
#pragma unroll
  for (int j = 0; j < 64; j += 4)
    *(float4*)(zr + j) = make_float4(z0[j] * sg, z0[j+1] * sg, z0[j+2] * sg, z0[j+3] * sg);
}

// ---------------- per-head k_, v, b ----------------
__global__ void __launch_bounds__(256)
k_kvb(const float* __restrict__ z, const float* __restrict__ wk,
      const float* __restrict__ wv, const float* __restrict__ wb,
      float* __restrict__ kb, float* __restrict__ vb, float* __restrict__ bb) {
  int e = blockIdx.x * 256 + threadIdx.x;
  if (e >= NE) return;
  const float* zr = z + (size_t)e * 64;
#pragma unroll 1
  for (int cc = 0; cc < 64; cc += 32) {
    float acc[32];
#pragma unroll
    for (int j = 0; j < 32; ++j) acc[j] = 0.f;
    gemm32<64>(zr, wk + cc, acc);
    store32(kb + (size_t)e * 64 + cc, acc);
  }
#pragma unroll 1
  for (int cc = 0; cc < 64; cc += 32) {
    float acc[32];
#pragma unroll
    for (int j = 0; j < 32; ++j) acc[j] = 0.f;
    gemm32<64>(zr, wv + cc, acc);
    store32(vb + (size_t)e * 64 + cc, acc);
  }
  float b = 0.f;
#pragma unroll 1
  for (int k = 0; k < 64; k += 2) {
    float2 z2 = *(const float2*)(zr + k);
    b = fmaf(z2.x, wb[k], b);
    b = fmaf(z2.y, wb[k + 1], b);
  }
  bb[e] = b;
}

// ---------------- per-head attention, fused m accumulate ----------------
__global__ void __launch_bounds__(256)
k_attn(const float* __restrict__ z, const float* __restrict__ kb,
       const float* __restrict__ vb, const float* __restrict__ bb,
       const int* __restrict__ klist,
       const float* __restrict__ wq, const float* __restrict__ wg,
       const float* __restrict__ bg,
       const float* __restrict__ wout, const float* __restrict__ bout,
       float* __restrict__ m, int first) {
  int e = blockIdx.x * 256 + threadIdx.x;
  if (e >= NE) return;
  const float* zr = z + (size_t)e * 64;

  // q = z @ wq (two 32-chunks kept in regs)
  float qa[32], qb[32];
#pragma unroll
  for (int j = 0; j < 32; ++j) qa[j] = 0.f;
  gemm32<64>(zr, wq, qa);
#pragma unroll
  for (int j = 0; j < 32; ++j) qb[j] = 0.f;
  gemm32<64>(zr, wq + 32, qb);

  int i2[8], j2[8];
#pragma unroll
  for (int kn = 0; kn < 8; ++kn) {
    i2[kn] = klist[(size_t)e * 16 + kn];
    j2[kn] = klist[(size_t)e * 16 + 8 + kn];
  }
  float alpha[8];
#pragma unroll 1
  for (int kn = 0; kn < 8; ++kn) {
    if (i2[kn] < 0) { alpha[kn] = -10000.0f; continue; }
    const float* kr = kb + (size_t)i2[kn] * 64;
    float d0 = 0.f, d1 = 0.f, d2 = 0.f, d3 = 0.f;
#pragma unroll
    for (int kk = 0; kk < 32; kk += 4) {
      float4 k4 = *(const float4*)(kr + kk);
      d0 = fmaf(k4.x, qa[kk + 0], d0); d1 = fmaf(k4.y, qa[kk + 1], d1);
      d2 = fmaf(k4.z, qa[kk + 2], d2); d3 = fmaf(k4.w, qa[kk + 3], d3);
    }
#pragma unroll
    for (int kk = 0; kk < 32; kk += 4) {
      float4 k4 = *(const float4*)(kr + 32 + kk);
      d0 = fmaf(k4.x, qb[kk + 0], d0); d1 = fmaf(k4.y, qb[kk + 1], d1);
      d2 = fmaf(k4.z, qb[kk + 2], d2); d3 = fmaf(k4.w, qb[kk + 3], d3);
    }
    alpha[kn] = (d0 + d1 + d2 + d3) * 0.125f + bb[j2[kn]];
  }
  float mx = alpha[0];
#pragma unroll
  for (int kn = 1; kn < 8; ++kn) mx = fmaxf(mx, alpha[kn]);
  float p[8], s = 0.f;
#pragma unroll
  for (int kn = 0; kn < 8; ++kn) { p[kn] = __expf(alpha[kn] - mx); s += p[kn]; }
  float is = 1.0f / s;
#pragma unroll
  for (int kn = 0; kn < 8; ++kn) p[kn] *= is;

  // mm = (first ? bout : m_row); then mm += ho @ wout, chunked over ho
  float mm[64];
  if (first) {
#pragma unroll
    for (int j = 0; j < 64; ++j) mm[j] = bout[j];
  } else {
#pragma unroll
    for (int j = 0; j < 64; j += 4) {
      float4 m4 = *(const float4*)(m + (size_t)e * 64 + j);
      mm[j] = m4.x; mm[j+1] = m4.y; mm[j+2] = m4.z; mm[j+3] = m4.w;
    }
  }

#pragma unroll 1
  for (int cc = 0; cc < 64; cc += 32) {
    // out chunk = sum_k p[k] * v[i2[k]][cc..cc+32)
    float out[32];
#pragma unroll
    for (int j = 0; j < 32; ++j) out[j] = 0.f;
#pragma unroll 1
    for (int kn = 0; kn < 8; ++kn) {
      int vi = (i2[kn] < 0) ? (NE - 1) : i2[kn];   // jax v[-1] wraps
      const float* vr = vb + (size_t)vi * 64 + cc;
      float pk = p[kn];
#pragma unroll
      for (int kk = 0; kk < 32; kk += 4) {
        float4 v4 = *(const float4*)(vr + kk);
        out[kk + 0] = fmaf(pk, v4.x, out[kk + 0]);
        out[kk + 1] = fmaf(pk, v4.y, out[kk + 1]);
        out[kk + 2] = fmaf(pk, v4.z, out[kk + 2]);
        out[kk + 3] = fmaf(pk, v4.w, out[kk + 3]);
      }
    }
    // gate chunk
    float g[32];
#pragma unroll
    for (int j = 0; j < 32; ++j) g[j] = bg[cc + j];
    gemm32<64>(zr, wg + cc, g);
#pragma unroll
    for (int j = 0; j < 32; ++j) out[j] *= fsig(g[j]);   // ho chunk
    // mm += ho_chunk @ wout[cc..cc+32, :]
#pragma unroll 1
    for (int k = 0; k < 32; ++k) {
      const float* wr = wout + (size_t)(cc + k) * 64;
      float x = out[k];
#pragma unroll
      for (int j = 0; j < 64; ++j) mm[j] = fmaf(x, wr[j], mm[j]);
    }
  }
#pragma unroll
  for (int j = 0; j < 64; j += 4)
    *(float4*)(m + (size_t)e * 64 + j) = make_float4(mm[j], mm[j+1], mm[j+2], mm[j+3]);
}

// ---------------- scatter m into m_sum ----------------
__global__ void __launch_bounds__(256)
k_scatter(const float* __restrict__ m, const int* __restrict__ edges,
          float* __restrict__ m_sum) {
  int i = blockIdx.x * 256 + threadIdx.x;
  if (i >= NE * 64) return;
  int e = i >> 6, j = i & 63;
  atomicAdd(&m_sum[(size_t)edges[e] * 64 + j], m[i]);
}

// ---------------- final node update ----------------
__global__ void __launch_bounds__(256)
k_final(const float* __restrict__ h, const float* __restrict__ na,
        const float* __restrict__ coord, const float* __restrict__ icoord,
        const float* __restrict__ m_sum, const float* __restrict__ x_sum,
        const float* __restrict__ cntf,
        const float* __restrict__ wh1, const float* __restrict__ bh1,
        const float* __restrict__ wh2, const float* __restrict__ bh2,
        float* __restrict__ scr,   // N x 64 staging
        float* __restrict__ out) {
  int n = blockIdx.x * 256 + threadIdx.x;
  if (n >= NN) return;
  float invc = 1.0f / fmaxf(cntf[n], 1.0f);

#pragma unroll
  for (int d = 0; d < 3; ++d)
    out[(size_t)NN * 64 + n * 3 + d] =
        0.2f * icoord[n * 3 + d] + 0.8f * coord[n * 3 + d] + x_sum[n * 3 + d] * invc;

  const float* hr = h  + (size_t)n * 64;
  const float* nr = na + (size_t)n * 64;
  const float* mr = m_sum + (size_t)n * 64;
  float* srow = scr + (size_t)n * 64;

#pragma unroll 1
  for (int cc = 0; cc < 64; cc += 32) {
    float acc[32];
#pragma unroll
    for (int j = 0; j < 32; ++j) acc[j] = bh1[cc + j];
    gemm32<64>(hr, wh1 + cc, acc);
    gemm32<64>(nr, wh1 + 64 * 64 + cc, acc);
    float macc[32];
#pragma unroll
    for (int j = 0; j < 32; ++j) macc[j] = 0.f;
    gemm32<64>(mr, wh1 + 128 * 64 + cc, macc);
#pragma unroll
    for (int j = 0; j < 32; ++j) acc[j] = fsilu(fmaf(invc, macc[j], acc[j]));
    store32(srow + cc, acc);
  }
#pragma unroll 1
  for (int cc = 0; cc < 64; cc += 32) {
    float acc[32];
#pragma unroll
    for (int j = 0; j < 32; ++j) acc[j] = bh2[cc + j];
    gemm32<64>(srow, wh2 + cc, acc);
#pragma unroll
    for (int j = 0; j < 32; j += 4) {
      float4 h4 = *(const float4*)(hr + cc + j);
      *(float4*)(out + (size_t)n * 64 + cc + j) =
          make_float4(acc[j] + h4.x, acc[j+1] + h4.y, acc[j+2] + h4.z, acc[j+3] + h4.w);
    }
  }
}

extern "C" void kernel_launch(void* const* d_in, const int* in_sizes, int n_in,
                              void* d_out, int out_size, void* d_ws, size_t ws_size,
                              hipStream_t stream) {
  (void)in_sizes; (void)n_in; (void)out_size; (void)ws_size;
  const float* h      = (const float*)d_in[0];
  const float* coord  = (const float*)d_in[1];
  const int*   edges  = (const int*)  d_in[2];
  const float* nvecs  = (const float*)d_in[3];
  const float* ea     = (const float*)d_in[4];
  const float* na     = (const float*)d_in[5];
  const float* icoord = (const float*)d_in[6];
  const int*   klist  = (const int*)  d_in[7];
  const float* w_chem1 = (const float*)d_in[8];
  const float* b_chem1 = (const float*)d_in[9];
  const float* w_chem2 = (const float*)d_in[10];
  const float* b_chem2 = (const float*)d_in[11];
  const float* w_pos1  = (const float*)d_in[12];
  const float* b_pos1  = (const float*)d_in[13];
  const float* w_pos2  = (const float*)d_in[14];
  const float* b_pos2  = (const float*)d_in[15];
  const float* w_sh    = (const float*)d_in[16];
  const float* b_sh    = (const float*)d_in[17];
  const float* w_att   = (const float*)d_in[18];
  const float* b_att   = (const float*)d_in[19];
  const float* wq      = (const float*)d_in[20];
  const float* wk      = (const float*)d_in[21];
  const float* wv      = (const float*)d_in[22];
  const float* wb      = (const float*)d_in[23];
  const float* wg      = (const float*)d_in[24];
  const float* bg      = (const float*)d_in[25];
  const float* w_out   = (const float*)d_in[26];
  const float* b_out   = (const float*)d_in[27];
  const float* wu1     = (const float*)d_in[28];
  const float* bu1     = (const float*)d_in[29];
  const float* wu2     = (const float*)d_in[30];
  const float* bu2     = (const float*)d_in[31];
  const float* wx1     = (const float*)d_in[32];
  const float* bx1     = (const float*)d_in[33];
  const float* wx2     = (const float*)d_in[34];
  const float* bx2     = (const float*)d_in[35];
  const float* wh1     = (const float*)d_in[36];
  const float* bh1     = (const float*)d_in[37];
  const float* wh2     = (const float*)d_in[38];
  const float* bh2     = (const float*)d_in[39];

  float* out = (float*)d_out;
  float* ws  = (float*)d_ws;
  // workspace layout (~167 MB), aggressively reused across phases:
  //   z    : k_pos acts staging       -> z
  //   kb   : k_chem acts / k_pos in   -> k_
  //   vb   : pos                      -> v
  //   mbuf : chem                     -> m accumulator
  float* z     = ws;
  float* kb    = z    + (size_t)NE * 64;
  float* vb    = kb   + (size_t)NE * 64;
  float* mbuf  = vb   + (size_t)NE * 64;
  float* ue    = mbuf + (size_t)NE * 64;   // E
  float* be    = ue   + NE;                // E
  float* m_sum = be   + NE;                // N x 64
  float* x_sum = m_sum + (size_t)NN * 64;  // N x 3
  float* cntf  = x_sum + (size_t)NN * 3;   // N
  float* nscr  = cntf + NN;                // N x 64 staging for k_final

  hipMemsetAsync(m_sum, 0, (size_t)(NN * 64 + NN * 3 + NN) * sizeof(float), stream);

  dim3 blk(256), grid((NE + 255) / 256);
  k_chem<<<grid, blk, 0, stream>>>(h, na, ea, edges, w_chem1, b_chem1, w_chem2, b_chem2,
                                   wu1, bu1, wu2, bu2, kb, mbuf, ue);
  k_pos<<<grid, blk, 0, stream>>>(coord, nvecs, ea, edges, w_pos1, b_pos1, w_pos2, b_pos2,
                                  wx1, bx1, wx2, bx2, ue, kb, z, vb, x_sum, cntf);
  k_z<<<grid, blk, 0, stream>>>(mbuf, vb, w_sh, b_sh, w_att, b_att, z);
  for (int hd = 0; hd < 4; ++hd) {
    k_kvb<<<grid, blk, 0, stream>>>(z, wk + hd * 4096, wv + hd * 4096, wb + hd * 64,
                                    kb, vb, be);
    k_attn<<<grid, blk, 0, stream>>>(z, kb, vb, be, klist,
                                     wq + hd * 4096, wg + hd * 4096, bg + hd * 64,
                                     w_out + hd * 64 * 64, b_out, mbuf, hd == 0 ? 1 : 0);
  }
  k_scatter<<<dim3((NE * 64) / 256), blk, 0, stream>>>(mbuf, edges, m_sum);
  k_final<<<dim3((NN + 255) / 256), blk, 0, stream>>>(h, na, coord, icoord, m_sum, x_sum,
                                                      cntf, wh1, bh1, wh2, bh2, nscr, out);
}